// Round 8
// baseline (316.307 us; speedup 1.0000x reference)
//
#include <hip/hip_runtime.h>
#include <hip/hip_bf16.h>
#include <math.h>

#define B_ 4096
#define I_ 1024
#define H_ 2048
#define K_ 3072   // I_ + H_
#define N4 8192   // 4 * H_
#define EPSGN 1e-5f

#define NT_K 96        // K_ / 32 k-tiles
#define APAN 8192      // A k-tile panel: 128 rows x 32 K bf16
#define BPAN 16384     // B k-tile panel: 256 cols x 32 K bf16 (2 halves of 8KB)
#define B_OFF 24576    // LDS offset of B region (A: 3 x 8KB)
// total dynamic LDS = 24576 + 3*16384 = 73728 bytes -> 2 blocks/CU

typedef __bf16 bf16;
typedef __bf16 bf16x8 __attribute__((ext_vector_type(8)));
typedef float  f32x4  __attribute__((ext_vector_type(4)));
typedef float  f32x16 __attribute__((ext_vector_type(16)));

__device__ __forceinline__ float sigm(float x) {
  return 1.0f / (1.0f + __expf(-x));
}
__device__ __forceinline__ float tanh_fast(float x) {
  float a = fabsf(x);
  float e = __expf(-2.0f * a);
  float t = (1.0f - e) / (1.0f + e);
  return copysignf(t, x);
}

// ---------- convA: [x|h_prev] -> tiled+swizzled bf16 panels ----------
// At[mt(32)][kt(96)][8KB]; panel byte(r, ks) = r*64 + ((ks ^ ((r>>1)&3))<<4),
// r in [0,128), ks in [0,4)  (slot_phys = ks_log ^ ((r>>1)&3), involution)
__global__ void convA(const float* __restrict__ x, const float* __restrict__ hp,
                      char* __restrict__ At) {
  int sid = blockIdx.x * blockDim.x + threadIdx.x;   // 16B slot id
  int p = sid & 511;
  int pan = sid >> 9;               // mt*96 + kt
  int mt = pan / 96;
  int kt = pan - mt * 96;
  int r = p >> 2;
  int ks = (p & 3) ^ ((r >> 1) & 3);
  int row = mt * 128 + r;
  int k = kt * 32 + ks * 8;
  const float* src = (k < I_) ? (x + (size_t)row * I_ + k)
                              : (hp + (size_t)row * H_ + (k - I_));
  f32x4 v0 = *(const f32x4*)src;
  f32x4 v1 = *(const f32x4*)(src + 4);
  bf16x8 o;
  o[0]=(bf16)v0[0]; o[1]=(bf16)v0[1]; o[2]=(bf16)v0[2]; o[3]=(bf16)v0[3];
  o[4]=(bf16)v1[0]; o[5]=(bf16)v1[1]; o[6]=(bf16)v1[2]; o[7]=(bf16)v1[3];
  *(bf16x8*)(At + (size_t)sid * 16) = o;
}

// ---------- convB: [Wg|Rg] -> tiled+swizzled bf16 panels ----------
// Bt[nt(32)][kt(96)][half(2)][8KB]; col n = nt*256 + h*128 + r
__global__ void convB(const float* __restrict__ Wi, const float* __restrict__ Wf,
                      const float* __restrict__ Wz, const float* __restrict__ Wo,
                      const float* __restrict__ Ri, const float* __restrict__ Rf,
                      const float* __restrict__ Rz, const float* __restrict__ Ro,
                      char* __restrict__ Bt) {
  int sid = blockIdx.x * blockDim.x + threadIdx.x;
  int p = sid & 511;
  int pan = sid >> 9;               // (nt*96 + kt)*2 + h
  int h = pan & 1;
  int pk = pan >> 1;
  int nt = pk / 96;
  int kt = pk - nt * 96;
  int r = p >> 2;
  int ks = (p & 3) ^ ((r >> 1) & 3);
  int n = nt * 256 + h * 128 + r;
  int g = n >> 11;
  int hr = n & 2047;
  int k = kt * 32 + ks * 8;
  const float* Wp = (g == 0) ? Wi : (g == 1) ? Wf : (g == 2) ? Wz : Wo;
  const float* Rp = (g == 0) ? Ri : (g == 1) ? Rf : (g == 2) ? Rz : Ro;
  const float* src = (k < I_) ? (Wp + (size_t)hr * I_ + k)
                              : (Rp + (size_t)hr * H_ + (k - I_));
  f32x4 v0 = *(const f32x4*)src;
  f32x4 v1 = *(const f32x4*)(src + 4);
  bf16x8 o;
  o[0]=(bf16)v0[0]; o[1]=(bf16)v0[1]; o[2]=(bf16)v0[2]; o[3]=(bf16)v0[3];
  o[4]=(bf16)v1[0]; o[5]=(bf16)v1[1]; o[6]=(bf16)v1[2]; o[7]=(bf16)v1[3];
  *(bf16x8*)(Bt + (size_t)sid * 16) = o;
}

// ---------- 128x256 GEMM, BK=32, 32x32x16 MFMA, 3-slot rings, 2 blocks/CU ----------
__device__ __forceinline__ void gload16(const char* g, char* l) {
  __builtin_amdgcn_global_load_lds(
      (const __attribute__((address_space(1))) void*)g,
      (__attribute__((address_space(3))) void*)l, 16, 0, 0);
}

__global__ __launch_bounds__(512, 4) void gemm8(const char* __restrict__ At,
                                                const char* __restrict__ Bt,
                                                bf16* __restrict__ pre) {
  extern __shared__ char lds[];
  const int tid = threadIdx.x;
  const int lane = tid & 63;
  const int wv = tid >> 6;       // 0..7
  const int wm = wv >> 2;        // 0..1 : rows wm*64..+63
  const int wn = wv & 3;         // 0..3 : cols wn*64..+63

  // L2-locality mapping: each XCD owns 4 bn-columns; its concurrent blocks
  // share one 1.5MB B-panel (L2-resident, reuse x32) and walk bm.
  // bijective: 8 xcd x 4 x 32 = 1024.
  const int xcd = blockIdx.x & 7;
  const int s = blockIdx.x >> 3;       // 0..127
  const int bn = xcd * 4 + (s >> 5);   // 0..31
  const int bm = s & 31;               // 0..31

  const char* a_src = At + (size_t)bm * (NT_K * APAN) + tid * 16;
  const char* b_src = Bt + (size_t)bn * (NT_K * BPAN) + tid * 16;
  char* a_lds = lds + tid * 16;
  char* b_lds = lds + B_OFF + tid * 16;

  // 32x32x16 fragment addressing: lane holds row/col = lane&31,
  // k = (lane>>5)*8 + e  -> k-slot(s) = s*2 + (lane>>5), swizzled like conv.
  const int l31 = lane & 31;
  const int q2  = lane >> 5;           // 0/1
  const int swz = (l31 >> 1) & 3;
  int lof[2];
  lof[0] = l31 * 64 + (((q2) ^ swz) << 4);          // kstep 0: slots {0,1}
  lof[1] = l31 * 64 + (((2 + q2) ^ swz) << 4);      // kstep 1: slots {2,3}
  const int aoffB = wm * 4096;                        // + mt*2048 + lof[s]
  const int boffB = (wn >> 1) * 8192 + (wn & 1) * 4096; // + nt*2048 + lof[s]
  const char* aL = lds;
  const char* bL = lds + B_OFF;

  f32x16 acc[2][2] = {};    // [mt][nt] 32x32 tiles
  bf16x8 af[2][2];          // [mt][kstep]
  bf16x8 b0[2], b1[2];      // [kstep] for nt=0 / nt=1

  // ---- prologue: A(0),B(0) -> slot0 ; A(1),B(1) -> slot1 ----
  gload16(a_src + 0 * APAN, a_lds + 0 * APAN);
  gload16(b_src + 0 * BPAN, b_lds + 0 * BPAN);
  gload16(b_src + 0 * BPAN + 8192, b_lds + 0 * BPAN + 8192);
  gload16(a_src + 1 * APAN, a_lds + 1 * APAN);
  gload16(b_src + 1 * BPAN, b_lds + 1 * BPAN);
  gload16(b_src + 1 * BPAN + 8192, b_lds + 1 * BPAN + 8192);
  asm volatile("s_waitcnt vmcnt(3)" ::: "memory");   // A(0)+B(0) landed
  __builtin_amdgcn_s_barrier();

  // pre-reads: a(0), b-nt0(0)
#pragma unroll
  for (int mt = 0; mt < 2; ++mt)
#pragma unroll
    for (int ks = 0; ks < 2; ++ks)
      af[mt][ks] = *(const bf16x8*)(aL + 0 * APAN + aoffB + mt * 2048 + lof[ks]);
#pragma unroll
  for (int ks = 0; ks < 2; ++ks)
    b0[ks] = *(const bf16x8*)(bL + 0 * BPAN + boffB + lof[ks]);

#pragma unroll 3
  for (int t = 0; t < NT_K; ++t) {
    const int sC = t % 3;            // current tile slot
    const int sN = (t + 1) % 3;      // next tile slot
    const int sP = (t + 2) % 3;      // prefetch target slot
    // ===== ph0: nt=0 -> acc[*][0]; stage A(t+2); read b-nt1(t) =====
    if (t + 2 < NT_K)
      gload16(a_src + (size_t)(t + 2) * APAN, a_lds + sP * APAN);
    __builtin_amdgcn_s_setprio(1);
#pragma unroll
    for (int ks = 0; ks < 2; ++ks)
#pragma unroll
      for (int mt = 0; mt < 2; ++mt)
        acc[mt][0] = __builtin_amdgcn_mfma_f32_32x32x16_bf16(
            af[mt][ks], b0[ks], acc[mt][0], 0, 0, 0);
    __builtin_amdgcn_s_setprio(0);
#pragma unroll
    for (int ks = 0; ks < 2; ++ks)
      b1[ks] = *(const bf16x8*)(bL + sC * BPAN + boffB + 2048 + lof[ks]);
    // certify A(t+1)+B(t+1) (everything except the A staged this phase);
    // tail (no ph0 stage): must drain fully — the R3 lesson.
    if (t < NT_K - 2)
      asm volatile("s_waitcnt vmcnt(1)" ::: "memory");
    else
      asm volatile("s_waitcnt vmcnt(0)" ::: "memory");
    __builtin_amdgcn_s_barrier();

    // ===== ph1: nt=1 -> acc[*][1]; stage B(t+2); read a(t+1), b-nt0(t+1) =====
    if (t + 2 < NT_K) {
      gload16(b_src + (size_t)(t + 2) * BPAN, b_lds + sP * BPAN);
      gload16(b_src + (size_t)(t + 2) * BPAN + 8192, b_lds + sP * BPAN + 8192);
    }
    __builtin_amdgcn_s_setprio(1);
#pragma unroll
    for (int ks = 0; ks < 2; ++ks)
#pragma unroll
      for (int mt = 0; mt < 2; ++mt)
        acc[mt][1] = __builtin_amdgcn_mfma_f32_32x32x16_bf16(
            af[mt][ks], b1[ks], acc[mt][1], 0, 0, 0);
    __builtin_amdgcn_s_setprio(0);
    if (t + 1 < NT_K) {
#pragma unroll
      for (int mt = 0; mt < 2; ++mt)
#pragma unroll
        for (int ks = 0; ks < 2; ++ks)
          af[mt][ks] = *(const bf16x8*)(aL + sN * APAN + aoffB + mt * 2048 + lof[ks]);
#pragma unroll
      for (int ks = 0; ks < 2; ++ks)
        b0[ks] = *(const bf16x8*)(bL + sN * BPAN + boffB + lof[ks]);
    }
    __builtin_amdgcn_s_barrier();
  }

  // ---- epilogue: bf16 C-write, 32x32 layout (m74/m101):
  //      col = lane&31, row = (reg&3) + 8*(reg>>2) + 4*(lane>>5) ----
#pragma unroll
  for (int mt = 0; mt < 2; ++mt)
#pragma unroll
    for (int nt = 0; nt < 2; ++nt) {
      const int colb = bn * 256 + wn * 64 + nt * 32 + l31;
      const int rowb = bm * 128 + wm * 64 + mt * 32 + 4 * q2;
#pragma unroll
      for (int g = 0; g < 4; ++g)
#pragma unroll
        for (int j = 0; j < 4; ++j) {
          int row = rowb + 8 * g + j;
          pre[(size_t)row * N4 + colb] = (bf16)acc[mt][nt][g * 4 + j];
        }
    }
}

// ---------- fused pointwise + GroupNorm: one block per batch row ----------
__global__ __launch_bounds__(256) void fusedpost(
    const bf16* __restrict__ pre,
    const float* __restrict__ bi, const float* __restrict__ bfp,
    const float* __restrict__ bz, const float* __restrict__ bo,
    const float* __restrict__ c_prev, const float* __restrict__ n_prev,
    const float* __restrict__ m_prev,
    const float* __restrict__ gnw, const float* __restrict__ gnb,
    float* __restrict__ out) {
  const int b = blockIdx.x;
  const int t = threadIdx.x;
  const int h0 = t * 8;
  const long PL = (long)B_ * H_;
  const long e = (long)b * H_ + h0;
  const bf16* prow = pre + (size_t)b * N4;

  bf16x8 PI = *(const bf16x8*)(prow + 0 * H_ + h0);
  bf16x8 PF = *(const bf16x8*)(prow + 1 * H_ + h0);
  bf16x8 PZ = *(const bf16x8*)(prow + 2 * H_ + h0);
  bf16x8 PO = *(const bf16x8*)(prow + 3 * H_ + h0);
  f32x4 BI0 = *(const f32x4*)(bi + h0),  BI1 = *(const f32x4*)(bi + h0 + 4);
  f32x4 BF0 = *(const f32x4*)(bfp + h0), BF1 = *(const f32x4*)(bfp + h0 + 4);
  f32x4 BZ0 = *(const f32x4*)(bz + h0),  BZ1 = *(const f32x4*)(bz + h0 + 4);
  f32x4 BO0 = *(const f32x4*)(bo + h0),  BO1 = *(const f32x4*)(bo + h0 + 4);
  f32x4 CP0 = *(const f32x4*)(c_prev + e), CP1 = *(const f32x4*)(c_prev + e + 4);
  f32x4 NP0 = *(const f32x4*)(n_prev + e), NP1 = *(const f32x4*)(n_prev + e + 4);
  f32x4 MP0 = *(const f32x4*)(m_prev + e), MP1 = *(const f32x4*)(m_prev + e + 4);

  float cs[8], og[8];
  f32x4 C0, C1, N0, N1, M0, M1;
  float sum = 0.f, sq = 0.f;
#pragma unroll
  for (int j = 0; j < 8; ++j) {
    float pi = (float)PI[j] + ((j < 4) ? BI0[j] : BI1[j - 4]);
    float pf = (float)PF[j] + ((j < 4) ? BF0[j] : BF1[j - 4]);
    float pz = (float)PZ[j] + ((j < 4) ? BZ0[j] : BZ1[j - 4]);
    float po = (float)PO[j] + ((j < 4) ? BO0[j] : BO1[j - 4]);
    float cp = (j < 4) ? CP0[j] : CP1[j - 4];
    float np = (j < 4) ? NP0[j] : NP1[j - 4];
    float mp = (j < 4) ? MP0[j] : MP1[j - 4];
    float ig = sigm(pi);
    float fg = sigm(pf);
    float zg = tanh_fast(pz);
    og[j] = sigm(po);
    float m = fmaxf(fg * mp, ig);
    float c = fg * cp + ig * zg;
    float n = fg * np + ig;
    if (j < 4) { C0[j] = c; N0[j] = n; M0[j] = m; }
    else       { C1[j-4] = c; N1[j-4] = n; M1[j-4] = m; }
    float v = c / n;
    cs[j] = v;
    sum += v;
    sq  += v * v;
  }
  *(f32x4*)(out + PL * 1 + e) = C0; *(f32x4*)(out + PL * 1 + e + 4) = C1;
  *(f32x4*)(out + PL * 2 + e) = N0; *(f32x4*)(out + PL * 2 + e + 4) = N1;
  *(f32x4*)(out + PL * 3 + e) = M0; *(f32x4*)(out + PL * 3 + e + 4) = M1;

#pragma unroll
  for (int off = 1; off < 64; off <<= 1) {
    sum += __shfl_xor(sum, off);
    sq  += __shfl_xor(sq, off);
  }
  __shared__ float s1[4], s2[4];
  const int wv = t >> 6, lane = t & 63;
  if (lane == 0) { s1[wv] = sum; s2[wv] = sq; }
  __syncthreads();
  sum = s1[0] + s1[1] + s1[2] + s1[3];
  sq  = s2[0] + s2[1] + s2[2] + s2[3];
  const float mu  = sum * (1.0f / H_);
  const float var = sq * (1.0f / H_) - mu * mu;
  const float rinv = rsqrtf(var + EPSGN);

  f32x4 GW0 = *(const f32x4*)(gnw + h0), GW1 = *(const f32x4*)(gnw + h0 + 4);
  f32x4 GB0 = *(const f32x4*)(gnb + h0), GB1 = *(const f32x4*)(gnb + h0 + 4);
  f32x4 Hh0, Hh1;
#pragma unroll
  for (int j = 0; j < 8; ++j) {
    float gw = (j < 4) ? GW0[j] : GW1[j - 4];
    float gb = (j < 4) ? GB0[j] : GB1[j - 4];
    float g = (cs[j] - mu) * rinv * gw + gb;
    float hv = og[j] * tanh_fast(g);
    if (j < 4) Hh0[j] = hv; else Hh1[j - 4] = hv;
  }
  *(f32x4*)(out + e) = Hh0;
  *(f32x4*)(out + e + 4) = Hh1;
}

// ---------- launch ----------
extern "C" void kernel_launch(void* const* d_in, const int* in_sizes, int n_in,
                              void* d_out, int out_size, void* d_ws, size_t ws_size,
                              hipStream_t stream) {
  const float* x      = (const float*)d_in[0];
  const float* h_prev = (const float*)d_in[1];
  const float* c_prev = (const float*)d_in[2];
  const float* n_prev = (const float*)d_in[3];
  const float* m_prev = (const float*)d_in[4];
  const float* Wi = (const float*)d_in[5];
  const float* Wf = (const float*)d_in[6];
  const float* Wz = (const float*)d_in[7];
  const float* Wo = (const float*)d_in[8];
  const float* bi = (const float*)d_in[9];
  const float* bf = (const float*)d_in[10];
  const float* bz = (const float*)d_in[11];
  const float* bo = (const float*)d_in[12];
  const float* Ri = (const float*)d_in[13];
  const float* Rf = (const float*)d_in[14];
  const float* Rz = (const float*)d_in[15];
  const float* Ro = (const float*)d_in[16];
  const float* gnw = (const float*)d_in[17];
  const float* gnb = (const float*)d_in[18];

  char* ws = (char*)d_ws;
  char* At = ws;                                             // 24 MiB
  char* Bt = ws + (size_t)B_ * K_ * 2;                       // 48 MiB
  bf16* pre = (bf16*)(ws + (size_t)B_ * K_ * 2 + (size_t)N4 * K_ * 2);  // 64 MiB
  float* out = (float*)d_out;

  hipFuncSetAttribute((const void*)gemm8,
                      hipFuncAttributeMaxDynamicSharedMemorySize, 73728);

  convA<<<((size_t)B_ * K_ / 8) / 256, 256, 0, stream>>>(x, h_prev, At);
  convB<<<((size_t)N4 * K_ / 8) / 256, 256, 0, stream>>>(Wi, Wf, Wz, Wo,
                                                         Ri, Rf, Rz, Ro, Bt);
  gemm8<<<1024, 512, 73728, stream>>>(At, Bt, pre);
  fusedpost<<<B_, 256, 0, stream>>>(pre, bi, bf, bz, bo,
                                    c_prev, n_prev, m_prev, gnw, gnb, out);
}

// Round 9
// 288.751 us; speedup vs baseline: 1.0954x; 1.0954x over previous
//
#include <hip/hip_runtime.h>
#include <hip/hip_bf16.h>
#include <math.h>

#define B_ 4096
#define I_ 1024
#define H_ 2048
#define K_ 3072   // I_ + H_
#define N4 8192   // 4 * H_
#define EPSGN 1e-5f

#define NT_K 96        // K_ / 32 k-tiles
#define APAN 8192      // A k-tile panel: 128 rows x 32 K bf16
#define BPAN 16384     // B k-tile panel: 256 cols x 32 K bf16 (2 halves of 8KB)
#define B_OFF 24576    // LDS offset of B region (A: 3 x 8KB)
// total dynamic LDS = 24576 + 3*16384 = 73728 bytes -> 2 blocks/CU

#define A_SLOTS (B_ * K_ / 8)            // 1572864 16B slots in At
#define B_SLOTS ((size_t)N4 * K_ / 8)    // 3145728 16B slots in Bt

typedef __bf16 bf16;
typedef __bf16 bf16x8 __attribute__((ext_vector_type(8)));
typedef float  f32x4  __attribute__((ext_vector_type(4)));

__device__ __forceinline__ float sigm(float x) {
  return 1.0f / (1.0f + __expf(-x));
}
__device__ __forceinline__ float tanh_fast(float x) {
  float a = fabsf(x);
  float e = __expf(-2.0f * a);
  float t = (1.0f - e) / (1.0f + e);
  return copysignf(t, x);
}

// ---------- merged conv: [x|h_prev] -> At panels, [Wg|Rg] -> Bt panels ----------
// Panel image (both): byte(r, ks) = r*64 + ((ks ^ ((r>>1)&3))<<4), r in [0,128),
// ks in [0,4)  (slot_phys = ks_log ^ ((r>>1)&3), involution; conv bakes inverse)
__global__ void convAB(const float* __restrict__ x, const float* __restrict__ hp,
                       const float* __restrict__ Wi, const float* __restrict__ Wf,
                       const float* __restrict__ Wz, const float* __restrict__ Wo,
                       const float* __restrict__ Ri, const float* __restrict__ Rf,
                       const float* __restrict__ Rz, const float* __restrict__ Ro,
                       char* __restrict__ At, char* __restrict__ Bt) {
  size_t sid = (size_t)blockIdx.x * blockDim.x + threadIdx.x;
  const float* src;
  char* dst;
  if (sid < A_SLOTS) {
    // At[mt(32)][kt(96)][8KB]
    int p = (int)(sid & 511);
    int pan = (int)(sid >> 9);        // mt*96 + kt
    int mt = pan / 96;
    int kt = pan - mt * 96;
    int r = p >> 2;
    int ks = (p & 3) ^ ((r >> 1) & 3);
    int row = mt * 128 + r;
    int k = kt * 32 + ks * 8;
    src = (k < I_) ? (x + (size_t)row * I_ + k)
                   : (hp + (size_t)row * H_ + (k - I_));
    dst = At + sid * 16;
  } else {
    // Bt[nt(32)][kt(96)][half(2)][8KB]; col n = nt*256 + h*128 + r
    size_t bsid = sid - A_SLOTS;
    if (bsid >= B_SLOTS) return;
    int p = (int)(bsid & 511);
    int pan = (int)(bsid >> 9);       // (nt*96 + kt)*2 + h
    int h = pan & 1;
    int pk = pan >> 1;
    int nt = pk / 96;
    int kt = pk - nt * 96;
    int r = p >> 2;
    int ks = (p & 3) ^ ((r >> 1) & 3);
    int n = nt * 256 + h * 128 + r;
    int g = n >> 11;
    int hr = n & 2047;
    int k = kt * 32 + ks * 8;
    const float* Wp = (g == 0) ? Wi : (g == 1) ? Wf : (g == 2) ? Wz : Wo;
    const float* Rp = (g == 0) ? Ri : (g == 1) ? Rf : (g == 2) ? Rz : Ro;
    src = (k < I_) ? (Wp + (size_t)hr * I_ + k)
                   : (Rp + (size_t)hr * H_ + (k - I_));
    dst = Bt + bsid * 16;
  }
  f32x4 v0 = *(const f32x4*)src;
  f32x4 v1 = *(const f32x4*)(src + 4);
  bf16x8 o;
  o[0]=(bf16)v0[0]; o[1]=(bf16)v0[1]; o[2]=(bf16)v0[2]; o[3]=(bf16)v0[3];
  o[4]=(bf16)v1[0]; o[5]=(bf16)v1[1]; o[6]=(bf16)v1[2]; o[7]=(bf16)v1[3];
  *(bf16x8*)dst = o;
}

// ---------- 128x256 GEMM, BK=32, 2 phases/ktile, 3-slot rings, 2 blocks/CU ----------
// (exact R7 kernel: 16x16x32 MFMA, conflict-free swizzle, audited ledger)
__device__ __forceinline__ void gload16(const char* g, char* l) {
  __builtin_amdgcn_global_load_lds(
      (const __attribute__((address_space(1))) void*)g,
      (__attribute__((address_space(3))) void*)l, 16, 0, 0);
}

__global__ __launch_bounds__(512, 4) void gemm8(const char* __restrict__ At,
                                                const char* __restrict__ Bt,
                                                bf16* __restrict__ pre) {
  extern __shared__ char lds[];
  const int tid = threadIdx.x;
  const int lane = tid & 63;
  const int wv = tid >> 6;       // 0..7
  const int wm = wv >> 2;        // 0..1 : rows wm*64..+63
  const int wn = wv & 3;         // 0..3 : cols wn*64..+63

  // L2-locality mapping: each XCD owns 4 bn-columns; its concurrent blocks
  // share one 1.5MB B-panel (L2-resident, reuse x32) and walk bm.
  // bijective: 8 xcd x 4 x 32 = 1024.
  const int xcd = blockIdx.x & 7;
  const int s = blockIdx.x >> 3;       // 0..127
  const int bn = xcd * 4 + (s >> 5);   // 0..31
  const int bm = s & 31;               // 0..31

  const char* a_src = At + (size_t)bm * (NT_K * APAN) + tid * 16;
  const char* b_src = Bt + (size_t)bn * (NT_K * BPAN) + tid * 16;
  char* a_lds = lds + tid * 16;
  char* b_lds = lds + B_OFF + tid * 16;

  const int l15 = lane & 15;
  const int q   = lane >> 4;
  const int loff = l15 * 64 + ((q ^ ((l15 >> 1) & 3)) << 4);
  const int aoff = wm * 4096 + loff;                         // + slot*8192 + mi*1024
  const int boff = (wn >> 1) * 8192 + (wn & 1) * 4096 + loff; // + slot*16384 + nj*1024
  const char* aL = lds;
  const char* bL = lds + B_OFF;

  f32x4 acc[4][4] = {};
  bf16x8 af[4], b0[2], b1[2];

  // ---- prologue: A(0),B(0) -> slot0 ; A(1),B(1) -> slot1 ----
  gload16(a_src + 0 * APAN, a_lds + 0 * APAN);
  gload16(b_src + 0 * BPAN, b_lds + 0 * BPAN);
  gload16(b_src + 0 * BPAN + 8192, b_lds + 0 * BPAN + 8192);
  gload16(a_src + 1 * APAN, a_lds + 1 * APAN);
  gload16(b_src + 1 * BPAN, b_lds + 1 * BPAN);
  gload16(b_src + 1 * BPAN + 8192, b_lds + 1 * BPAN + 8192);
  asm volatile("s_waitcnt vmcnt(3)" ::: "memory");   // A(0)+B(0) landed
  __builtin_amdgcn_s_barrier();

  // pre-reads: a(0), n0(0)
#pragma unroll
  for (int mi = 0; mi < 4; ++mi)
    af[mi] = *(const bf16x8*)(aL + 0 * APAN + aoff + mi * 1024);
#pragma unroll
  for (int nj = 0; nj < 2; ++nj)
    b0[nj] = *(const bf16x8*)(bL + 0 * BPAN + boff + nj * 1024);

#pragma unroll 3
  for (int t = 0; t < NT_K; ++t) {
    const int sC = t % 3;            // current tile slot
    const int sN = (t + 1) % 3;      // next tile slot
    const int sP = (t + 2) % 3;      // prefetch target slot
    // ===== ph0: a(t) x n0(t) -> acc[*][0..1]; stage A(t+2); read n1(t) =====
    if (t + 2 < NT_K)
      gload16(a_src + (size_t)(t + 2) * APAN, a_lds + sP * APAN);
    __builtin_amdgcn_s_setprio(1);
#pragma unroll
    for (int mi = 0; mi < 4; ++mi)
#pragma unroll
      for (int nj = 0; nj < 2; ++nj)
        acc[mi][nj] = __builtin_amdgcn_mfma_f32_16x16x32_bf16(
            af[mi], b0[nj], acc[mi][nj], 0, 0, 0);
    __builtin_amdgcn_s_setprio(0);
#pragma unroll
    for (int nj = 0; nj < 2; ++nj)
      b1[nj] = *(const bf16x8*)(bL + sC * BPAN + boff + (2 + nj) * 1024);
    // certify A(t+1)+B(t+1) (everything except the A staged this phase);
    // tail (no ph0 stage): must drain fully — the R3 lesson.
    if (t < NT_K - 2)
      asm volatile("s_waitcnt vmcnt(1)" ::: "memory");
    else
      asm volatile("s_waitcnt vmcnt(0)" ::: "memory");
    __builtin_amdgcn_s_barrier();

    // ===== ph1: a(t) x n1(t) -> acc[*][2..3]; stage B(t+2); read a(t+1), n0(t+1) =====
    if (t + 2 < NT_K) {
      gload16(b_src + (size_t)(t + 2) * BPAN, b_lds + sP * BPAN);
      gload16(b_src + (size_t)(t + 2) * BPAN + 8192, b_lds + sP * BPAN + 8192);
    }
    __builtin_amdgcn_s_setprio(1);
#pragma unroll
    for (int mi = 0; mi < 4; ++mi)
#pragma unroll
      for (int nj = 0; nj < 2; ++nj)
        acc[mi][2 + nj] = __builtin_amdgcn_mfma_f32_16x16x32_bf16(
            af[mi], b1[nj], acc[mi][2 + nj], 0, 0, 0);
    __builtin_amdgcn_s_setprio(0);
    if (t + 1 < NT_K) {
#pragma unroll
      for (int mi = 0; mi < 4; ++mi)
        af[mi] = *(const bf16x8*)(aL + sN * APAN + aoff + mi * 1024);
#pragma unroll
      for (int nj = 0; nj < 2; ++nj)
        b0[nj] = *(const bf16x8*)(bL + sN * BPAN + boff + nj * 1024);
    }
    __builtin_amdgcn_s_barrier();
  }

  // ---- epilogue: bf16 C-write (layout m89/m91: col=lane&15, row=(lane>>4)*4+j) ----
  const int crow0 = (lane >> 4) * 4;
  const int ccol  = lane & 15;
#pragma unroll
  for (int mi = 0; mi < 4; ++mi)
#pragma unroll
    for (int nj = 0; nj < 4; ++nj)
#pragma unroll
      for (int j = 0; j < 4; ++j) {
        int row = bm * 128 + wm * 64 + mi * 16 + crow0 + j;
        int col = bn * 256 + wn * 64 + nj * 16 + ccol;
        pre[(size_t)row * N4 + col] = (bf16)acc[mi][nj][j];
      }
}

// ---------- fused pointwise + GroupNorm: one block per batch row ----------
__global__ __launch_bounds__(256) void fusedpost(
    const bf16* __restrict__ pre,
    const float* __restrict__ bi, const float* __restrict__ bfp,
    const float* __restrict__ bz, const float* __restrict__ bo,
    const float* __restrict__ c_prev, const float* __restrict__ n_prev,
    const float* __restrict__ m_prev,
    const float* __restrict__ gnw, const float* __restrict__ gnb,
    float* __restrict__ out) {
  const int b = blockIdx.x;
  const int t = threadIdx.x;
  const int h0 = t * 8;
  const long PL = (long)B_ * H_;
  const long e = (long)b * H_ + h0;
  const bf16* prow = pre + (size_t)b * N4;

  bf16x8 PI = *(const bf16x8*)(prow + 0 * H_ + h0);
  bf16x8 PF = *(const bf16x8*)(prow + 1 * H_ + h0);
  bf16x8 PZ = *(const bf16x8*)(prow + 2 * H_ + h0);
  bf16x8 PO = *(const bf16x8*)(prow + 3 * H_ + h0);
  f32x4 BI0 = *(const f32x4*)(bi + h0),  BI1 = *(const f32x4*)(bi + h0 + 4);
  f32x4 BF0 = *(const f32x4*)(bfp + h0), BF1 = *(const f32x4*)(bfp + h0 + 4);
  f32x4 BZ0 = *(const f32x4*)(bz + h0),  BZ1 = *(const f32x4*)(bz + h0 + 4);
  f32x4 BO0 = *(const f32x4*)(bo + h0),  BO1 = *(const f32x4*)(bo + h0 + 4);
  f32x4 CP0 = *(const f32x4*)(c_prev + e), CP1 = *(const f32x4*)(c_prev + e + 4);
  f32x4 NP0 = *(const f32x4*)(n_prev + e), NP1 = *(const f32x4*)(n_prev + e + 4);
  f32x4 MP0 = *(const f32x4*)(m_prev + e), MP1 = *(const f32x4*)(m_prev + e + 4);

  float cs[8], og[8];
  f32x4 C0, C1, N0, N1, M0, M1;
  float sum = 0.f, sq = 0.f;
#pragma unroll
  for (int j = 0; j < 8; ++j) {
    float pi = (float)PI[j] + ((j < 4) ? BI0[j] : BI1[j - 4]);
    float pf = (float)PF[j] + ((j < 4) ? BF0[j] : BF1[j - 4]);
    float pz = (float)PZ[j] + ((j < 4) ? BZ0[j] : BZ1[j - 4]);
    float po = (float)PO[j] + ((j < 4) ? BO0[j] : BO1[j - 4]);
    float cp = (j < 4) ? CP0[j] : CP1[j - 4];
    float np = (j < 4) ? NP0[j] : NP1[j - 4];
    float mp = (j < 4) ? MP0[j] : MP1[j - 4];
    float ig = sigm(pi);
    float fg = sigm(pf);
    float zg = tanh_fast(pz);
    og[j] = sigm(po);
    float m = fmaxf(fg * mp, ig);
    float c = fg * cp + ig * zg;
    float n = fg * np + ig;
    if (j < 4) { C0[j] = c; N0[j] = n; M0[j] = m; }
    else       { C1[j-4] = c; N1[j-4] = n; M1[j-4] = m; }
    float v = c / n;
    cs[j] = v;
    sum += v;
    sq  += v * v;
  }
  *(f32x4*)(out + PL * 1 + e) = C0; *(f32x4*)(out + PL * 1 + e + 4) = C1;
  *(f32x4*)(out + PL * 2 + e) = N0; *(f32x4*)(out + PL * 2 + e + 4) = N1;
  *(f32x4*)(out + PL * 3 + e) = M0; *(f32x4*)(out + PL * 3 + e + 4) = M1;

#pragma unroll
  for (int off = 1; off < 64; off <<= 1) {
    sum += __shfl_xor(sum, off);
    sq  += __shfl_xor(sq, off);
  }
  __shared__ float s1[4], s2[4];
  const int wv = t >> 6, lane = t & 63;
  if (lane == 0) { s1[wv] = sum; s2[wv] = sq; }
  __syncthreads();
  sum = s1[0] + s1[1] + s1[2] + s1[3];
  sq  = s2[0] + s2[1] + s2[2] + s2[3];
  const float mu  = sum * (1.0f / H_);
  const float var = sq * (1.0f / H_) - mu * mu;
  const float rinv = rsqrtf(var + EPSGN);

  f32x4 GW0 = *(const f32x4*)(gnw + h0), GW1 = *(const f32x4*)(gnw + h0 + 4);
  f32x4 GB0 = *(const f32x4*)(gnb + h0), GB1 = *(const f32x4*)(gnb + h0 + 4);
  f32x4 Hh0, Hh1;
#pragma unroll
  for (int j = 0; j < 8; ++j) {
    float gw = (j < 4) ? GW0[j] : GW1[j - 4];
    float gb = (j < 4) ? GB0[j] : GB1[j - 4];
    float g = (cs[j] - mu) * rinv * gw + gb;
    float hv = og[j] * tanh_fast(g);
    if (j < 4) Hh0[j] = hv; else Hh1[j - 4] = hv;
  }
  *(f32x4*)(out + e) = Hh0;
  *(f32x4*)(out + e + 4) = Hh1;
}

// ---------- launch ----------
extern "C" void kernel_launch(void* const* d_in, const int* in_sizes, int n_in,
                              void* d_out, int out_size, void* d_ws, size_t ws_size,
                              hipStream_t stream) {
  const float* x      = (const float*)d_in[0];
  const float* h_prev = (const float*)d_in[1];
  const float* c_prev = (const float*)d_in[2];
  const float* n_prev = (const float*)d_in[3];
  const float* m_prev = (const float*)d_in[4];
  const float* Wi = (const float*)d_in[5];
  const float* Wf = (const float*)d_in[6];
  const float* Wz = (const float*)d_in[7];
  const float* Wo = (const float*)d_in[8];
  const float* bi = (const float*)d_in[9];
  const float* bf = (const float*)d_in[10];
  const float* bz = (const float*)d_in[11];
  const float* bo = (const float*)d_in[12];
  const float* Ri = (const float*)d_in[13];
  const float* Rf = (const float*)d_in[14];
  const float* Rz = (const float*)d_in[15];
  const float* Ro = (const float*)d_in[16];
  const float* gnw = (const float*)d_in[17];
  const float* gnb = (const float*)d_in[18];

  char* ws = (char*)d_ws;
  char* At = ws;                                             // 24 MiB
  char* Bt = ws + (size_t)B_ * K_ * 2;                       // 48 MiB
  bf16* pre = (bf16*)(ws + (size_t)B_ * K_ * 2 + (size_t)N4 * K_ * 2);  // 64 MiB
  float* out = (float*)d_out;

  hipFuncSetAttribute((const void*)gemm8,
                      hipFuncAttributeMaxDynamicSharedMemorySize, 73728);

  const int conv_blocks = (int)((A_SLOTS + B_SLOTS + 255) / 256);
  convAB<<<conv_blocks, 256, 0, stream>>>(x, h_prev, Wi, Wf, Wz, Wo,
                                          Ri, Rf, Rz, Ro, At, Bt);
  gemm8<<<1024, 512, 73728, stream>>>(At, Bt, pre);
  fusedpost<<<B_, 256, 0, stream>>>(pre, bi, bf, bz, bo,
                                    c_prev, n_prev, m_prev, gnw, gnb, out);
}